// Round 3
// baseline (213.750 us; speedup 1.0000x reference)
//
#include <hip/hip_runtime.h>
#include <stdint.h>
#include <stddef.h>

// gcnmask: N=50000, DEG=16, F=128. Edges grouped by dst (dst = e/16) -> no atomics.
// R11: gather-MLP restructure. edge_k/out_k re-mapped so ONE dwordx4 VMEM instruction
//      gathers FOUR src rows (16 lanes x 16 B per row): lane=(q=lane>>4, li=lane&15),
//      lane loads features [li*8, li*8+8) of edge-slot q. Gather instruction count
//      drops 4x (R10: ~136 VMEM/wave, one edge-row each -> ~38/wave, 4 edges each),
//      raising MLP per latency slot 4x. Per-feature sums cross quarters -> shfl_xor
//      (16,32) butterfly. zy_k now stores Ez=exp2(z') bf16 (edge_k has zero exp2).

#define NNODES 50000
#define DEG    16
#define FD     128

#define NEG_LOG2E -1.44269504f

typedef __bf16 bf16x8 __attribute__((ext_vector_type(8)));
typedef short  s16x8  __attribute__((ext_vector_type(8)));
typedef float  f32x4  __attribute__((ext_vector_type(4)));
typedef float  f32x2  __attribute__((ext_vector_type(2)));

__device__ __forceinline__ short f2bf_s(float f) {
    union { float f; uint32_t u; } v; v.f = f;
    uint32_t r = v.u + 0x7fffu + ((v.u >> 16) & 1u);   // RNE
    return (short)(r >> 16);
}
__device__ __forceinline__ float bflo(uint32_t u) {
    union { uint32_t u; float f; } v; v.u = u << 16;
    return v.f;
}
__device__ __forceinline__ float bfhi(uint32_t u) {
    union { uint32_t u; float f; } v; v.u = u & 0xffff0000u;
    return v.f;
}

// Pack Wmb[k][c] (c<128: Wm_top; c>=128: Wm_bot), PRE-SCALED by -log2e, and weight
// (unscaled) into bf16 B-fragment order: idx = ((kk*NT+ntile)*64 + q*16 + n15)*8 + (k&7).
__global__ __launch_bounds__(256) void pack_k(const float* __restrict__ wm,
                                              const float* __restrict__ w,
                                              short* __restrict__ wmb,
                                              short* __restrict__ wpack) {
    int tid = blockIdx.x * 256 + threadIdx.x;
    if (tid < 128 * 256) {
        int k = tid >> 8, c = tid & 255;
        float v = (c < 128) ? wm[k * 128 + c] : wm[(128 + k) * 128 + (c - 128)];
        int idx = (((k >> 5) * 16 + (c >> 4)) * 64 + ((k >> 3) & 3) * 16 + (c & 15)) * 8 + (k & 7);
        wmb[idx] = f2bf_s(NEG_LOG2E * v);
    }
    if (tid < 128 * 128) {
        int k = tid >> 7, n = tid & 127;
        int idx = (((k >> 5) * 8 + (n >> 4)) * 64 + ((k >> 3) & 3) * 16 + (n & 15)) * 8 + (k & 7);
        wpack[idx] = f2bf_s(w[tid]);
    }
}

// ZY' = x @ Wmb' ([50000x128]@[128x256]). Block = 16 nodes, 4 waves.
// Epilogue via LDS transpose, coalesced writes:
//   c<128  -> ezb bf16 pairs (Ez = exp2(z') rows)
//   c>=128 -> xb bf16 pairs (x rows, 256 B) + y8 fp8 E-rows (E = exp2(y'), 128 B)
__global__ __launch_bounds__(256) void zy_k(const float* __restrict__ x,
                                            const short* __restrict__ wmb,
                                            short* __restrict__ ezb,
                                            uint32_t* __restrict__ xb,
                                            uint8_t* __restrict__ y8) {
    __shared__ float ct[16 * 260];
    const int tid = threadIdx.x, wave = tid >> 6, lane = tid & 63;
    const int q = lane >> 4, m = lane & 15;
    const int node0 = blockIdx.x * 16;

    f32x4 acc[4];
    #pragma unroll
    for (int nt = 0; nt < 4; ++nt) acc[nt] = (f32x4){0.f, 0.f, 0.f, 0.f};

    #pragma unroll
    for (int kk = 0; kk < 4; ++kk) {
        const float* rp = x + (size_t)(node0 + m) * FD + kk * 32 + q * 8;
        f32x4 lo = *reinterpret_cast<const f32x4*>(rp);
        f32x4 hi = *reinterpret_cast<const f32x4*>(rp + 4);
        bf16x8 a;
        a[0]=(__bf16)lo.x; a[1]=(__bf16)lo.y; a[2]=(__bf16)lo.z; a[3]=(__bf16)lo.w;
        a[4]=(__bf16)hi.x; a[5]=(__bf16)hi.y; a[6]=(__bf16)hi.z; a[7]=(__bf16)hi.w;
        #pragma unroll
        for (int nt = 0; nt < 4; ++nt) {
            int frag = kk * 16 + wave * 4 + nt;
            s16x8 braw = *reinterpret_cast<const s16x8*>(wmb + ((size_t)frag * 64 + lane) * 8);
            acc[nt] = __builtin_amdgcn_mfma_f32_16x16x32_bf16(a, __builtin_bit_cast(bf16x8, braw), acc[nt], 0, 0, 0);
        }
    }
    #pragma unroll
    for (int nt = 0; nt < 4; ++nt)
        #pragma unroll
        for (int i = 0; i < 4; ++i)
            ct[(q * 4 + i) * 260 + wave * 64 + nt * 16 + m] = acc[nt][i];
    __syncthreads();

    const int row = tid >> 4;                 // 0..15
    const int c0  = (tid & 15) * 16;          // 0..240
    const int grow = node0 + row;
    if (c0 < 128) {
        // Ez = exp2(z') -> bf16 pairs. Range: exp2(+-40) well inside bf16.
        uint32_t zo[8];
        #pragma unroll
        for (int j = 0; j < 8; ++j) {
            float v0 = __builtin_amdgcn_exp2f(ct[row * 260 + c0 + 2 * j]);
            float v1 = __builtin_amdgcn_exp2f(ct[row * 260 + c0 + 2 * j + 1]);
            zo[j] = (uint32_t)(uint16_t)f2bf_s(v0) | ((uint32_t)(uint16_t)f2bf_s(v1) << 16);
        }
        uint4* dst = reinterpret_cast<uint4*>(ezb + (size_t)grow * FD + c0);
        dst[0] = make_uint4(zo[0], zo[1], zo[2], zo[3]);
        dst[1] = make_uint4(zo[4], zo[5], zo[6], zo[7]);
    } else {
        const int f0 = c0 - 128;
        const float* xr = x + (size_t)grow * FD + f0;   // L1-hot
        // x -> bf16 pairs (8 uints)
        uint32_t xo[8];
        #pragma unroll
        for (int j = 0; j < 8; ++j) {
            float v0 = xr[2 * j], v1 = xr[2 * j + 1];
            xo[j] = (uint32_t)(uint16_t)f2bf_s(v0) | ((uint32_t)(uint16_t)f2bf_s(v1) << 16);
        }
        uint4* xdst = reinterpret_cast<uint4*>(xb + (size_t)grow * 64 + f0 / 2);
        xdst[0] = make_uint4(xo[0], xo[1], xo[2], xo[3]);
        xdst[1] = make_uint4(xo[4], xo[5], xo[6], xo[7]);
        // E = exp2(y') -> fp8 (16 bytes = 4 dwords). cvt_pk_fp8 saturates to +-448;
        // overflow/underflow map to g~0 / g=1 exactly where the true sigmoid saturates.
        uint32_t yo[4];
        #pragma unroll
        for (int g = 0; g < 4; ++g) {
            float y0 = __builtin_amdgcn_exp2f(ct[row * 260 + c0 + 4 * g]);
            float y1 = __builtin_amdgcn_exp2f(ct[row * 260 + c0 + 4 * g + 1]);
            float y2 = __builtin_amdgcn_exp2f(ct[row * 260 + c0 + 4 * g + 2]);
            float y3 = __builtin_amdgcn_exp2f(ct[row * 260 + c0 + 4 * g + 3]);
            int u = __builtin_amdgcn_cvt_pk_fp8_f32(y0, y1, 0, false);
            u     = __builtin_amdgcn_cvt_pk_fp8_f32(y2, y3, u, true);
            yo[g] = (uint32_t)u;
        }
        *reinterpret_cast<uint4*>(y8 + (size_t)grow * 128 + f0) = make_uint4(yo[0], yo[1], yo[2], yo[3]);
    }
}

// x_new = x + sum_e sigmoid * x[src], sigmoid = rcp(fma(Ez[dst], E[src], 1)).
// Wave = 4 dst nodes. Lane (q=lane>>4, li=lane&15): owns features [li*8, li*8+8) of
// edge-slot q. One dwordx4 gather covers 4 src rows (16 lanes x 16 B each). Per-feature
// sum over 16 edges = 4 per-lane partials + shfl_xor(16,32) butterfly.
__global__ __launch_bounds__(256) void edge_k(const short* __restrict__ ezb,
                                              const uint32_t* __restrict__ xb,
                                              const uint8_t* __restrict__ y8,
                                              const int* __restrict__ esrc,
                                              uint32_t* __restrict__ xnb) {
    const int tid = threadIdx.x, wave = tid >> 6, lane = tid & 63;
    const int q = lane >> 4, li = lane & 15;
    const int n0 = __builtin_amdgcn_readfirstlane(blockIdx.x * 16 + wave * 4);

    float acc[4][8];
    #pragma unroll
    for (int d = 0; d < 4; ++d)
        #pragma unroll
        for (int j = 0; j < 8; ++j) acc[d][j] = 0.f;

    #pragma unroll
    for (int d = 0; d < 4; ++d) {
        const int nd = n0 + d;
        const int* ep = esrc + nd * DEG;
        int se[4];
        #pragma unroll
        for (int i = 0; i < 4; ++i) se[i] = ep[i * 4 + q];   // per-lane (q) vector load

        uint4 xw[4]; uint2 yw[4];
        #pragma unroll
        for (int i = 0; i < 4; ++i) {
            xw[i] = *reinterpret_cast<const uint4*>(xb + (size_t)se[i] * 64 + li * 4);
            yw[i] = *reinterpret_cast<const uint2*>(y8 + (size_t)se[i] * 128 + li * 8);
        }
        uint4 ez = *reinterpret_cast<const uint4*>(
            reinterpret_cast<const uint32_t*>(ezb) + (size_t)nd * 64 + li * 4);
        float Ez[8] = {bflo(ez.x), bfhi(ez.x), bflo(ez.y), bfhi(ez.y),
                       bflo(ez.z), bfhi(ez.z), bflo(ez.w), bfhi(ez.w)};
        #pragma unroll
        for (int i = 0; i < 4; ++i) {
            f32x2 p0 = __builtin_amdgcn_cvt_pk_f32_fp8((int)yw[i].x, false);
            f32x2 p1 = __builtin_amdgcn_cvt_pk_f32_fp8((int)yw[i].x, true);
            f32x2 p2 = __builtin_amdgcn_cvt_pk_f32_fp8((int)yw[i].y, false);
            f32x2 p3 = __builtin_amdgcn_cvt_pk_f32_fp8((int)yw[i].y, true);
            float E[8]  = {p0.x, p0.y, p1.x, p1.y, p2.x, p2.y, p3.x, p3.y};
            float xf[8] = {bflo(xw[i].x), bfhi(xw[i].x), bflo(xw[i].y), bfhi(xw[i].y),
                           bflo(xw[i].z), bfhi(xw[i].z), bflo(xw[i].w), bfhi(xw[i].w)};
            #pragma unroll
            for (int j = 0; j < 8; ++j) {
                float g = __builtin_amdgcn_rcpf(__builtin_fmaf(Ez[j], E[j], 1.f));
                acc[d][j] = __builtin_fmaf(g, xf[j], acc[d][j]);
            }
        }
    }

    // Reduce across quarters (lanes l, l^16, l^32, l^48 hold same features, diff edges).
    #pragma unroll
    for (int d = 0; d < 4; ++d)
        #pragma unroll
        for (int j = 0; j < 8; ++j) {
            float v = acc[d][j];
            v += __shfl_xor(v, 16, 64);
            v += __shfl_xor(v, 32, 64);
            acc[d][j] = v;
        }

    // Lane writes dst n0+q, features [li*8, li*8+8): one dwordx4 store covers 4 rows.
    const bool q1 = (q & 1) != 0, q2 = (q & 2) != 0;
    uint4 cw = *reinterpret_cast<const uint4*>(xb + (size_t)(n0 + q) * 64 + li * 4);
    uint32_t cwv[4] = {cw.x, cw.y, cw.z, cw.w};
    uint32_t outw[4];
    #pragma unroll
    for (int k = 0; k < 4; ++k) {
        float t0 = q1 ? acc[1][2 * k]     : acc[0][2 * k];
        float t1 = q1 ? acc[3][2 * k]     : acc[2][2 * k];
        float slo = q2 ? t1 : t0;
        float u0 = q1 ? acc[1][2 * k + 1] : acc[0][2 * k + 1];
        float u1 = q1 ? acc[3][2 * k + 1] : acc[2][2 * k + 1];
        float shi = q2 ? u1 : u0;
        float r0 = bflo(cwv[k]) + slo;
        float r1 = bfhi(cwv[k]) + shi;
        outw[k] = (uint32_t)(uint16_t)f2bf_s(r0) | ((uint32_t)(uint16_t)f2bf_s(r1) << 16);
    }
    *reinterpret_cast<uint4*>(xnb + (size_t)(n0 + q) * 64 + li * 4) =
        make_uint4(outw[0], outw[1], outw[2], outw[3]);
}

// out = (sum_e adj*x_new[src]) @ weight + bias. Block = 16 nodes, 4 waves x 4 nodes.
// Phase A: same 4-rows-per-instruction gather of xnb + butterfly -> xn LDS (f32).
// Phase B: [16x128]@[128x128] MFMA with fused bias.
__global__ __launch_bounds__(256) void out_k(const uint32_t* __restrict__ xnb,
                                             const float* __restrict__ adj,
                                             const int* __restrict__ esrc,
                                             const short* __restrict__ wpack,
                                             const float* __restrict__ bias,
                                             float* __restrict__ out) {
    __shared__ float xn[16 * 132];
    const int tid = threadIdx.x, wave = tid >> 6, lane = tid & 63;
    const int q = lane >> 4, m = lane & 15;
    const int li = m;
    const int node0 = blockIdx.x * 16;
    const int n0 = __builtin_amdgcn_readfirstlane(node0 + wave * 4);

    float acc[4][8];
    #pragma unroll
    for (int d = 0; d < 4; ++d)
        #pragma unroll
        for (int j = 0; j < 8; ++j) acc[d][j] = 0.f;

    #pragma unroll
    for (int d = 0; d < 4; ++d) {
        const int nd = n0 + d;
        const int* ep = esrc + nd * DEG;
        const float* ap = adj + nd * DEG;
        int se[4]; float wv[4];
        #pragma unroll
        for (int i = 0; i < 4; ++i) { se[i] = ep[i * 4 + q]; wv[i] = ap[i * 4 + q]; }

        uint4 uw[4];
        #pragma unroll
        for (int i = 0; i < 4; ++i)
            uw[i] = *reinterpret_cast<const uint4*>(xnb + (size_t)se[i] * 64 + li * 4);

        #pragma unroll
        for (int i = 0; i < 4; ++i) {
            float xf[8] = {bflo(uw[i].x), bfhi(uw[i].x), bflo(uw[i].y), bfhi(uw[i].y),
                           bflo(uw[i].z), bfhi(uw[i].z), bflo(uw[i].w), bfhi(uw[i].w)};
            #pragma unroll
            for (int j = 0; j < 8; ++j)
                acc[d][j] = __builtin_fmaf(wv[i], xf[j], acc[d][j]);
        }
    }

    #pragma unroll
    for (int d = 0; d < 4; ++d)
        #pragma unroll
        for (int j = 0; j < 8; ++j) {
            float v = acc[d][j];
            v += __shfl_xor(v, 16, 64);
            v += __shfl_xor(v, 32, 64);
            acc[d][j] = v;
        }

    // Lane stores dst-row wave*4+q, features [li*8, li*8+8) to LDS (f32).
    const bool q1 = (q & 1) != 0, q2 = (q & 2) != 0;
    const int r = wave * 4 + q;
    float fin[8];
    #pragma unroll
    for (int j = 0; j < 8; ++j) {
        float t0 = q1 ? acc[1][j] : acc[0][j];
        float t1 = q1 ? acc[3][j] : acc[2][j];
        fin[j] = q2 ? t1 : t0;
    }
    *reinterpret_cast<f32x4*>(&xn[r * 132 + li * 8])     = (f32x4){fin[0], fin[1], fin[2], fin[3]};
    *reinterpret_cast<f32x4*>(&xn[r * 132 + li * 8 + 4]) = (f32x4){fin[4], fin[5], fin[6], fin[7]};
    __syncthreads();

    f32x4 sacc[2];
    sacc[0] = (f32x4){0.f, 0.f, 0.f, 0.f};
    sacc[1] = (f32x4){0.f, 0.f, 0.f, 0.f};
    #pragma unroll
    for (int kk = 0; kk < 4; ++kk) {
        const float* p = &xn[m * 132 + kk * 32 + q * 8];
        bf16x8 a;
        a[0]=(__bf16)p[0]; a[1]=(__bf16)p[1]; a[2]=(__bf16)p[2]; a[3]=(__bf16)p[3];
        a[4]=(__bf16)p[4]; a[5]=(__bf16)p[5]; a[6]=(__bf16)p[6]; a[7]=(__bf16)p[7];
        #pragma unroll
        for (int t = 0; t < 2; ++t) {
            int nt = wave * 2 + t;
            s16x8 braw = *reinterpret_cast<const s16x8*>(wpack + ((size_t)(kk * 8 + nt) * 64 + lane) * 8);
            sacc[t] = __builtin_amdgcn_mfma_f32_16x16x32_bf16(a, __builtin_bit_cast(bf16x8, braw), sacc[t], 0, 0, 0);
        }
    }
    #pragma unroll
    for (int t = 0; t < 2; ++t) {
        const int f = (wave * 2 + t) * 16 + m;
        const float bv = bias[f];
        #pragma unroll
        for (int i = 0; i < 4; ++i)
            out[(size_t)(node0 + q * 4 + i) * FD + f] = sacc[t][i] + bv;
    }
}

extern "C" void kernel_launch(void* const* d_in, const int* in_sizes, int n_in,
                              void* d_out, int out_size, void* d_ws, size_t ws_size,
                              hipStream_t stream) {
    const float* x      = (const float*)d_in[0];
    const float* weight = (const float*)d_in[1];
    const float* bias   = (const float*)d_in[2];
    const float* wm     = (const float*)d_in[3];
    const float* adj    = (const float*)d_in[4];
    const int*   esrc   = (const int*)d_in[5];
    // d_in[6] edge_dst unused: dst(e) = e/16 by construction.

    // ws: [0,64K) wmb | [64K,96K) wpack | [96K,+12.8M) ezb | [+12.8M,+25.6M) xnb.
    // d_out scratch phase: [0,12.8M) xb (bf16 x rows) | [12.8M,+6.4M) y8 (fp8 E rows);
    // both fully consumed by edge_k before out_k overwrites d_out with the real output.
    short*    wmb   = (short*)d_ws;
    short*    wpack = (short*)((char*)d_ws + 65536);
    short*    ezb   = (short*)((char*)d_ws + 98304);
    uint32_t* xnb   = (uint32_t*)((char*)d_ws + 98304 + (size_t)NNODES * FD * 2);
    uint32_t* xb    = (uint32_t*)d_out;
    uint8_t*  y8    = (uint8_t*)d_out + (size_t)NNODES * FD * 2;
    float*    out   = (float*)d_out;

    pack_k <<<128,         256, 0, stream>>>(wm, weight, wmb, wpack);
    zy_k   <<<NNODES / 16, 256, 0, stream>>>(x, wmb, ezb, xb, y8);
    edge_k <<<NNODES / 16, 256, 0, stream>>>(ezb, xb, y8, esrc, xnb);
    out_k  <<<NNODES / 16, 256, 0, stream>>>(xnb, adj, esrc, wpack, bias, out);
}

// Round 4
// 181.491 us; speedup vs baseline: 1.1777x; 1.1777x over previous
//
#include <hip/hip_runtime.h>
#include <stdint.h>
#include <stddef.h>

// gcnmask: N=50000, DEG=16, F=128. Edges grouped by dst (dst = e/16) -> no atomics.
// R12: lane-local 4-row gather. R11's cross-quarter butterfly + acc[d] selection let
//      instcombine form select-of-GEP -> acc arrays demoted to scratch (out_k WRITE
//      153.4 MB = out 25.6 + acc 102.4 + fin 25.6 -- exact match). New mapping: lane
//      (q=lane>>4, li=lane&15) owns node n0+q, features [li*8,li*8+8), iterates its own
//      16 edges. Quarters still cover 4 src rows per dwordx4 (same VMEM efficiency),
//      but reduction is lane-local: 8 NAMED float accumulators, no arrays, no shfl.

#define NNODES 50000
#define DEG    16
#define FD     128

#define NEG_LOG2E -1.44269504f

typedef __bf16 bf16x8 __attribute__((ext_vector_type(8)));
typedef short  s16x8  __attribute__((ext_vector_type(8)));
typedef float  f32x4  __attribute__((ext_vector_type(4)));
typedef float  f32x2  __attribute__((ext_vector_type(2)));

__device__ __forceinline__ short f2bf_s(float f) {
    union { float f; uint32_t u; } v; v.f = f;
    uint32_t r = v.u + 0x7fffu + ((v.u >> 16) & 1u);   // RNE
    return (short)(r >> 16);
}
__device__ __forceinline__ float bflo(uint32_t u) {
    union { uint32_t u; float f; } v; v.u = u << 16;
    return v.f;
}
__device__ __forceinline__ float bfhi(uint32_t u) {
    union { uint32_t u; float f; } v; v.u = u & 0xffff0000u;
    return v.f;
}
__device__ __forceinline__ uint32_t pkbf(float lo, float hi) {
    return (uint32_t)(uint16_t)f2bf_s(lo) | ((uint32_t)(uint16_t)f2bf_s(hi) << 16);
}

// Pack Wmb[k][c] (c<128: Wm_top; c>=128: Wm_bot), PRE-SCALED by -log2e, and weight
// (unscaled) into bf16 B-fragment order: idx = ((kk*NT+ntile)*64 + q*16 + n15)*8 + (k&7).
__global__ __launch_bounds__(256) void pack_k(const float* __restrict__ wm,
                                              const float* __restrict__ w,
                                              short* __restrict__ wmb,
                                              short* __restrict__ wpack) {
    int tid = blockIdx.x * 256 + threadIdx.x;
    if (tid < 128 * 256) {
        int k = tid >> 8, c = tid & 255;
        float v = (c < 128) ? wm[k * 128 + c] : wm[(128 + k) * 128 + (c - 128)];
        int idx = (((k >> 5) * 16 + (c >> 4)) * 64 + ((k >> 3) & 3) * 16 + (c & 15)) * 8 + (k & 7);
        wmb[idx] = f2bf_s(NEG_LOG2E * v);
    }
    if (tid < 128 * 128) {
        int k = tid >> 7, n = tid & 127;
        int idx = (((k >> 5) * 8 + (n >> 4)) * 64 + ((k >> 3) & 3) * 16 + (n & 15)) * 8 + (k & 7);
        wpack[idx] = f2bf_s(w[tid]);
    }
}

// ZY' = x @ Wmb' ([50000x128]@[128x256]). Block = 16 nodes, 4 waves.
// Epilogue via LDS transpose, coalesced writes:
//   c<128  -> ezb bf16 pairs (Ez = exp2(z') rows)
//   c>=128 -> xb bf16 pairs (x rows, 256 B) + y8 fp8 E-rows (E = exp2(y'), 128 B)
__global__ __launch_bounds__(256) void zy_k(const float* __restrict__ x,
                                            const short* __restrict__ wmb,
                                            short* __restrict__ ezb,
                                            uint32_t* __restrict__ xb,
                                            uint8_t* __restrict__ y8) {
    __shared__ float ct[16 * 260];
    const int tid = threadIdx.x, wave = tid >> 6, lane = tid & 63;
    const int q = lane >> 4, m = lane & 15;
    const int node0 = blockIdx.x * 16;

    f32x4 acc[4];
    #pragma unroll
    for (int nt = 0; nt < 4; ++nt) acc[nt] = (f32x4){0.f, 0.f, 0.f, 0.f};

    #pragma unroll
    for (int kk = 0; kk < 4; ++kk) {
        const float* rp = x + (size_t)(node0 + m) * FD + kk * 32 + q * 8;
        f32x4 lo = *reinterpret_cast<const f32x4*>(rp);
        f32x4 hi = *reinterpret_cast<const f32x4*>(rp + 4);
        bf16x8 a;
        a[0]=(__bf16)lo.x; a[1]=(__bf16)lo.y; a[2]=(__bf16)lo.z; a[3]=(__bf16)lo.w;
        a[4]=(__bf16)hi.x; a[5]=(__bf16)hi.y; a[6]=(__bf16)hi.z; a[7]=(__bf16)hi.w;
        #pragma unroll
        for (int nt = 0; nt < 4; ++nt) {
            int frag = kk * 16 + wave * 4 + nt;
            s16x8 braw = *reinterpret_cast<const s16x8*>(wmb + ((size_t)frag * 64 + lane) * 8);
            acc[nt] = __builtin_amdgcn_mfma_f32_16x16x32_bf16(a, __builtin_bit_cast(bf16x8, braw), acc[nt], 0, 0, 0);
        }
    }
    #pragma unroll
    for (int nt = 0; nt < 4; ++nt)
        #pragma unroll
        for (int i = 0; i < 4; ++i)
            ct[(q * 4 + i) * 260 + wave * 64 + nt * 16 + m] = acc[nt][i];
    __syncthreads();

    const int row = tid >> 4;                 // 0..15
    const int c0  = (tid & 15) * 16;          // 0..240
    const int grow = node0 + row;
    if (c0 < 128) {
        // Ez = exp2(z') -> bf16 pairs. z' ~ N(0,1.44^2) -> exp2 range well inside bf16.
        uint32_t zo[8];
        #pragma unroll
        for (int j = 0; j < 8; ++j) {
            float v0 = __builtin_amdgcn_exp2f(ct[row * 260 + c0 + 2 * j]);
            float v1 = __builtin_amdgcn_exp2f(ct[row * 260 + c0 + 2 * j + 1]);
            zo[j] = pkbf(v0, v1);
        }
        uint4* dst = reinterpret_cast<uint4*>(ezb + (size_t)grow * FD + c0);
        dst[0] = make_uint4(zo[0], zo[1], zo[2], zo[3]);
        dst[1] = make_uint4(zo[4], zo[5], zo[6], zo[7]);
    } else {
        const int f0 = c0 - 128;
        const float* xr = x + (size_t)grow * FD + f0;   // L1-hot
        // x -> bf16 pairs (8 uints)
        uint32_t xo[8];
        #pragma unroll
        for (int j = 0; j < 8; ++j) {
            float v0 = xr[2 * j], v1 = xr[2 * j + 1];
            xo[j] = pkbf(v0, v1);
        }
        uint4* xdst = reinterpret_cast<uint4*>(xb + (size_t)grow * 64 + f0 / 2);
        xdst[0] = make_uint4(xo[0], xo[1], xo[2], xo[3]);
        xdst[1] = make_uint4(xo[4], xo[5], xo[6], xo[7]);
        // E = exp2(y') -> fp8 (16 bytes = 4 dwords). cvt_pk_fp8 saturates to +-448;
        // overflow/underflow map to g~0 / g=1 exactly where the true sigmoid saturates.
        uint32_t yo[4];
        #pragma unroll
        for (int g = 0; g < 4; ++g) {
            float y0 = __builtin_amdgcn_exp2f(ct[row * 260 + c0 + 4 * g]);
            float y1 = __builtin_amdgcn_exp2f(ct[row * 260 + c0 + 4 * g + 1]);
            float y2 = __builtin_amdgcn_exp2f(ct[row * 260 + c0 + 4 * g + 2]);
            float y3 = __builtin_amdgcn_exp2f(ct[row * 260 + c0 + 4 * g + 3]);
            int u = __builtin_amdgcn_cvt_pk_fp8_f32(y0, y1, 0, false);
            u     = __builtin_amdgcn_cvt_pk_fp8_f32(y2, y3, u, true);
            yo[g] = (uint32_t)u;
        }
        *reinterpret_cast<uint4*>(y8 + (size_t)grow * 128 + f0) = make_uint4(yo[0], yo[1], yo[2], yo[3]);
    }
}

// x_new = x + sum_e sigmoid * x[src], sigmoid = rcp(fma(Ez[dst], E[src], 1)).
// Wave = 4 dst nodes, one per quarter. Lane (q,li): node n0+q, features [li*8,li*8+8),
// iterates its node's 16 edges. Each dwordx4/dwordx2 gather covers 4 src rows (one per
// quarter). Lane-local accumulation into 8 named scalars -> no arrays, no scratch.
__global__ __launch_bounds__(256) void edge_k(const short* __restrict__ ezb,
                                              const uint32_t* __restrict__ xb,
                                              const uint8_t* __restrict__ y8,
                                              const int* __restrict__ esrc,
                                              uint32_t* __restrict__ xnb) {
    const int tid = threadIdx.x, wave = tid >> 6, lane = tid & 63;
    const int q = lane >> 4, li = lane & 15;
    const int n0 = __builtin_amdgcn_readfirstlane(blockIdx.x * 16 + wave * 4);
    const int nd = n0 + q;                       // per-lane node (uniform within quarter)

    // Edge list of nd: 4 x int4, quarter-uniform address (broadcast loads).
    const int4* ep = reinterpret_cast<const int4*>(esrc + nd * DEG);
    const int4 s0 = ep[0], s1 = ep[1], s2 = ep[2], s3 = ep[3];

    // Ez row + center-x row of nd: one dwordx4 covers 4 quarters' rows.
    const uint4 ez = *reinterpret_cast<const uint4*>(
        reinterpret_cast<const uint32_t*>(ezb) + (size_t)nd * 64 + li * 4);
    const uint4 cw = *reinterpret_cast<const uint4*>(xb + (size_t)nd * 64 + li * 4);

    // Issue ALL 16 edge gathers into named registers (max MLP, nothing demotable).
    uint4 xw0, xw1, xw2, xw3, xw4, xw5, xw6, xw7, xw8, xw9, xw10, xw11, xw12, xw13, xw14, xw15;
    uint2 yw0, yw1, yw2, yw3, yw4, yw5, yw6, yw7, yw8, yw9, yw10, yw11, yw12, yw13, yw14, yw15;
#define LD(I, S) \
    xw##I = *reinterpret_cast<const uint4*>(xb + (size_t)(S) * 64 + li * 4); \
    yw##I = *reinterpret_cast<const uint2*>(y8 + (size_t)(S) * 128 + li * 8);
    LD(0, s0.x)  LD(1, s0.y)  LD(2, s0.z)  LD(3, s0.w)
    LD(4, s1.x)  LD(5, s1.y)  LD(6, s1.z)  LD(7, s1.w)
    LD(8, s2.x)  LD(9, s2.y)  LD(10, s2.z) LD(11, s2.w)
    LD(12, s3.x) LD(13, s3.y) LD(14, s3.z) LD(15, s3.w)
#undef LD

    const float Ez0 = bflo(ez.x), Ez1 = bfhi(ez.x), Ez2 = bflo(ez.y), Ez3 = bfhi(ez.y),
                Ez4 = bflo(ez.z), Ez5 = bfhi(ez.z), Ez6 = bflo(ez.w), Ez7 = bfhi(ez.w);
    float a0 = 0.f, a1 = 0.f, a2 = 0.f, a3 = 0.f, a4 = 0.f, a5 = 0.f, a6 = 0.f, a7 = 0.f;
#define ACC(I) { \
    f32x2 p0 = __builtin_amdgcn_cvt_pk_f32_fp8((int)yw##I.x, false); \
    f32x2 p1 = __builtin_amdgcn_cvt_pk_f32_fp8((int)yw##I.x, true);  \
    f32x2 p2 = __builtin_amdgcn_cvt_pk_f32_fp8((int)yw##I.y, false); \
    f32x2 p3 = __builtin_amdgcn_cvt_pk_f32_fp8((int)yw##I.y, true);  \
    a0 = __builtin_fmaf(__builtin_amdgcn_rcpf(__builtin_fmaf(Ez0, p0.x, 1.f)), bflo(xw##I.x), a0); \
    a1 = __builtin_fmaf(__builtin_amdgcn_rcpf(__builtin_fmaf(Ez1, p0.y, 1.f)), bfhi(xw##I.x), a1); \
    a2 = __builtin_fmaf(__builtin_amdgcn_rcpf(__builtin_fmaf(Ez2, p1.x, 1.f)), bflo(xw##I.y), a2); \
    a3 = __builtin_fmaf(__builtin_amdgcn_rcpf(__builtin_fmaf(Ez3, p1.y, 1.f)), bfhi(xw##I.y), a3); \
    a4 = __builtin_fmaf(__builtin_amdgcn_rcpf(__builtin_fmaf(Ez4, p2.x, 1.f)), bflo(xw##I.z), a4); \
    a5 = __builtin_fmaf(__builtin_amdgcn_rcpf(__builtin_fmaf(Ez5, p2.y, 1.f)), bfhi(xw##I.z), a5); \
    a6 = __builtin_fmaf(__builtin_amdgcn_rcpf(__builtin_fmaf(Ez6, p3.x, 1.f)), bflo(xw##I.w), a6); \
    a7 = __builtin_fmaf(__builtin_amdgcn_rcpf(__builtin_fmaf(Ez7, p3.y, 1.f)), bfhi(xw##I.w), a7); }
    ACC(0)  ACC(1)  ACC(2)  ACC(3)
    ACC(4)  ACC(5)  ACC(6)  ACC(7)
    ACC(8)  ACC(9)  ACC(10) ACC(11)
    ACC(12) ACC(13) ACC(14) ACC(15)
#undef ACC

    const uint32_t o0 = pkbf(bflo(cw.x) + a0, bfhi(cw.x) + a1);
    const uint32_t o1 = pkbf(bflo(cw.y) + a2, bfhi(cw.y) + a3);
    const uint32_t o2 = pkbf(bflo(cw.z) + a4, bfhi(cw.z) + a5);
    const uint32_t o3 = pkbf(bflo(cw.w) + a6, bfhi(cw.w) + a7);
    *reinterpret_cast<uint4*>(xnb + (size_t)nd * 64 + li * 4) = make_uint4(o0, o1, o2, o3);
}

// out = (sum_e adj*x_new[src]) @ weight + bias. Block = 16 nodes, 4 waves.
// Phase A: lane-local 4-row gather (same mapping as edge_k) -> xn LDS (f32).
// Phase B: [16x128]@[128x128] MFMA with fused bias (unchanged, proven).
__global__ __launch_bounds__(256) void out_k(const uint32_t* __restrict__ xnb,
                                             const float* __restrict__ adj,
                                             const int* __restrict__ esrc,
                                             const short* __restrict__ wpack,
                                             const float* __restrict__ bias,
                                             float* __restrict__ out) {
    __shared__ float xn[16 * 132];
    const int tid = threadIdx.x, wave = tid >> 6, lane = tid & 63;
    const int q = lane >> 4, m = lane & 15;
    const int li = m;
    const int node0 = blockIdx.x * 16;
    const int n0 = __builtin_amdgcn_readfirstlane(node0 + wave * 4);
    const int nd = n0 + q;

    const int4* ep = reinterpret_cast<const int4*>(esrc + nd * DEG);
    const int4 s0 = ep[0], s1 = ep[1], s2 = ep[2], s3 = ep[3];
    const float4* ap = reinterpret_cast<const float4*>(adj + nd * DEG);
    const float4 w0 = ap[0], w1 = ap[1], w2 = ap[2], w3 = ap[3];

    uint4 u0, u1, u2, u3, u4, u5, u6, u7, u8, u9, u10, u11, u12, u13, u14, u15;
#define LD(I, S) u##I = *reinterpret_cast<const uint4*>(xnb + (size_t)(S) * 64 + li * 4);
    LD(0, s0.x)  LD(1, s0.y)  LD(2, s0.z)  LD(3, s0.w)
    LD(4, s1.x)  LD(5, s1.y)  LD(6, s1.z)  LD(7, s1.w)
    LD(8, s2.x)  LD(9, s2.y)  LD(10, s2.z) LD(11, s2.w)
    LD(12, s3.x) LD(13, s3.y) LD(14, s3.z) LD(15, s3.w)
#undef LD

    float a0 = 0.f, a1 = 0.f, a2 = 0.f, a3 = 0.f, a4 = 0.f, a5 = 0.f, a6 = 0.f, a7 = 0.f;
#define ACC(I, W) \
    a0 = __builtin_fmaf(W, bflo(u##I.x), a0); a1 = __builtin_fmaf(W, bfhi(u##I.x), a1); \
    a2 = __builtin_fmaf(W, bflo(u##I.y), a2); a3 = __builtin_fmaf(W, bfhi(u##I.y), a3); \
    a4 = __builtin_fmaf(W, bflo(u##I.z), a4); a5 = __builtin_fmaf(W, bfhi(u##I.z), a5); \
    a6 = __builtin_fmaf(W, bflo(u##I.w), a6); a7 = __builtin_fmaf(W, bfhi(u##I.w), a7);
    ACC(0, w0.x)  ACC(1, w0.y)  ACC(2, w0.z)  ACC(3, w0.w)
    ACC(4, w1.x)  ACC(5, w1.y)  ACC(6, w1.z)  ACC(7, w1.w)
    ACC(8, w2.x)  ACC(9, w2.y)  ACC(10, w2.z) ACC(11, w2.w)
    ACC(12, w3.x) ACC(13, w3.y) ACC(14, w3.z) ACC(15, w3.w)
#undef ACC

    const int r = wave * 4 + q;
    *reinterpret_cast<f32x4*>(&xn[r * 132 + li * 8])     = (f32x4){a0, a1, a2, a3};
    *reinterpret_cast<f32x4*>(&xn[r * 132 + li * 8 + 4]) = (f32x4){a4, a5, a6, a7};
    __syncthreads();

    f32x4 sacc[2];
    sacc[0] = (f32x4){0.f, 0.f, 0.f, 0.f};
    sacc[1] = (f32x4){0.f, 0.f, 0.f, 0.f};
    #pragma unroll
    for (int kk = 0; kk < 4; ++kk) {
        const float* p = &xn[m * 132 + kk * 32 + q * 8];
        bf16x8 a;
        a[0]=(__bf16)p[0]; a[1]=(__bf16)p[1]; a[2]=(__bf16)p[2]; a[3]=(__bf16)p[3];
        a[4]=(__bf16)p[4]; a[5]=(__bf16)p[5]; a[6]=(__bf16)p[6]; a[7]=(__bf16)p[7];
        #pragma unroll
        for (int t = 0; t < 2; ++t) {
            int nt = wave * 2 + t;
            s16x8 braw = *reinterpret_cast<const s16x8*>(wpack + ((size_t)(kk * 8 + nt) * 64 + lane) * 8);
            sacc[t] = __builtin_amdgcn_mfma_f32_16x16x32_bf16(a, __builtin_bit_cast(bf16x8, braw), sacc[t], 0, 0, 0);
        }
    }
    #pragma unroll
    for (int t = 0; t < 2; ++t) {
        const int f = (wave * 2 + t) * 16 + m;
        const float bv = bias[f];
        #pragma unroll
        for (int i = 0; i < 4; ++i)
            out[(size_t)(node0 + q * 4 + i) * FD + f] = sacc[t][i] + bv;
    }
}

extern "C" void kernel_launch(void* const* d_in, const int* in_sizes, int n_in,
                              void* d_out, int out_size, void* d_ws, size_t ws_size,
                              hipStream_t stream) {
    const float* x      = (const float*)d_in[0];
    const float* weight = (const float*)d_in[1];
    const float* bias   = (const float*)d_in[2];
    const float* wm     = (const float*)d_in[3];
    const float* adj    = (const float*)d_in[4];
    const int*   esrc   = (const int*)d_in[5];
    // d_in[6] edge_dst unused: dst(e) = e/16 by construction.

    // ws: [0,64K) wmb | [64K,96K) wpack | [96K,+12.8M) ezb | [+12.8M,+25.6M) xnb.
    // d_out scratch phase: [0,12.8M) xb (bf16 x rows) | [12.8M,+6.4M) y8 (fp8 E rows);
    // both fully consumed by edge_k before out_k overwrites d_out with the real output.
    short*    wmb   = (short*)d_ws;
    short*    wpack = (short*)((char*)d_ws + 65536);
    short*    ezb   = (short*)((char*)d_ws + 98304);
    uint32_t* xnb   = (uint32_t*)((char*)d_ws + 98304 + (size_t)NNODES * FD * 2);
    uint32_t* xb    = (uint32_t*)d_out;
    uint8_t*  y8    = (uint8_t*)d_out + (size_t)NNODES * FD * 2;
    float*    out   = (float*)d_out;

    pack_k <<<128,         256, 0, stream>>>(wm, weight, wmb, wpack);
    zy_k   <<<NNODES / 16, 256, 0, stream>>>(x, wmb, ezb, xb, y8);
    edge_k <<<NNODES / 16, 256, 0, stream>>>(ezb, xb, y8, esrc, xnb);
    out_k  <<<NNODES / 16, 256, 0, stream>>>(xnb, adj, esrc, wpack, bias, out);
}